// Round 10
// baseline (444.169 us; speedup 1.0000x reference)
//
#include <hip/hip_runtime.h>

// Binary-weight 3x3 conv via implicit GEMM on int8 MFMA.
// out[co, p] = (1/26) * sum_k wb[co,k] * q26(im2col(x))[k,p],  exact i32 accum.
// Round 10: R7 structure with double (not quad) LDS buffers -> 60KB LDS and
// VGPR<=128 (__launch_bounds__(512,4)) so TWO blocks co-reside per CU.
// The per-step barrier drain is now hidden by the other block's waves
// (m97/m114 implicit cross-block overlap), which no prior round had.
// Loop: stage(u+1 -> buf^1) ; read frags + 28 MFMA on buf ; __syncthreads().

#define N_ 32
#define C_ 256
#define H_ 56
#define W_ 56
#define HP 58
#define SPATIAL (H_ * W_)          // 3136
#define P_TOTAL (N_ * SPATIAL)     // 100352
#define BNP 224
#define NBLK (P_TOTAL / BNP)       // 448
#define NSUB 36                    // 4 ci-slices(64) * 9 taps
#define QSCALE 26.0f
#define QINV (1.0f / 26.0f)

typedef __attribute__((ext_vector_type(4))) int int32x4;

#define GLOAD_LDS16(g, l) __builtin_amdgcn_global_load_lds(                 \
    (const __attribute__((address_space(1))) void*)(g),                     \
    (__attribute__((address_space(3))) void*)(l), 16, 0, 0)

// ---------------- prep kernels ----------------

__global__ void xform_w(const float* __restrict__ w, char* __restrict__ wt) {
    const int co = blockIdx.x;
    const int ci = threadIdx.x;
    const float* wp = w + ((size_t)co * C_ + ci) * 9;
    #pragma unroll
    for (int tap = 0; tap < 9; ++tap)
        wt[((size_t)tap * C_ + co) * C_ + ci] = (wp[tap] >= 0.f) ? (char)1 : (char)-1;
}

// NCHW f32 -> padded NHWC i8 (q = clamp(rint(26x)); pad = -26). Block = (n,h).
__global__ __launch_bounds__(256) void xform_x(const float* __restrict__ x,
                                               unsigned char* __restrict__ xt) {
    __shared__ unsigned char lds8[64 * 272];   // [w][ci], stride 272 (16-mult)
    const int b = blockIdx.x;                  // n*56 + h
    const int n = b / H_;
    const int h = b - n * H_;
    const int t = threadIdx.x;
    const int wq = t >> 6;                     // ci quarter
    const int wv = t & 63;                     // w lane
    const float* xp = x + (((size_t)n * C_ + wq * 64) * H_ + h) * W_ + wv;

    #pragma unroll 4
    for (int c4 = 0; c4 < 64; c4 += 4) {
        unsigned int pk = 0;
        #pragma unroll
        for (int j = 0; j < 4; ++j) {
            float v = (wv < W_) ? xp[(size_t)(c4 + j) * SPATIAL] : 0.f;
            int q = (int)rintf(v * QSCALE);
            q = q < -127 ? -127 : (q > 127 ? 127 : q);
            pk |= ((unsigned int)(q & 255)) << (8 * j);
        }
        if (wv < W_)
            *reinterpret_cast<unsigned int*>(&lds8[wv * 272 + wq * 64 + c4]) = pk;
    }
    __syncthreads();

    unsigned char* rowp = xt + (((size_t)n * HP + h + 1) * HP) * C_;
    {   // interior: w = 1..56, 64B (4x16B) per thread along ci
        const int ww = t & 63, cq = t >> 6;
        if (ww < W_) {
            #pragma unroll
            for (int j = 0; j < 4; ++j) {
                int32x4 v = *reinterpret_cast<const int32x4*>(
                    &lds8[ww * 272 + cq * 64 + j * 16]);
                *reinterpret_cast<int32x4*>(rowp + (size_t)(ww + 1) * C_ + cq * 64 + j * 16) = v;
            }
        }
    }
    if (t < 64) {   // pad cols w=0 and w=57 (0xE6 = -26)
        reinterpret_cast<unsigned int*>(rowp)[t] = 0xE6E6E6E6u;
        reinterpret_cast<unsigned int*>(rowp + (size_t)57 * C_)[t] = 0xE6E6E6E6u;
    }
    if (h == 0) {   // pad rows 0 and 57 once per n
        unsigned int* r0  = reinterpret_cast<unsigned int*>(xt + ((size_t)n * HP) * HP * C_);
        unsigned int* r57 = reinterpret_cast<unsigned int*>(xt + (((size_t)n * HP + 57) * HP) * C_);
        for (int idx = t; idx < HP * C_ / 4; idx += 256) {
            r0[idx]  = 0xE6E6E6E6u;
            r57[idx] = 0xE6E6E6E6u;
        }
    }
}

// ---------------- main GEMM ----------------
// grid = 448 blocks (XCD-swizzled), 512 threads = 8 waves (4 co x 2 p).
// Wave (wm,wn): 64 co x 112 p = 4x7 16x16x64 i8 fragments.
// Step u (36): cbh = u/9 (64-ci slice), tap = u%9 (fastest -> L2 tap reuse).
// LDS: A dbuf 2x16KB @0, B dbuf 2x14KB @32768. 60KB total, 2 blocks/CU.

__global__ __launch_bounds__(512, 4) void bgemm(const unsigned char* __restrict__ xt,
                                                const unsigned char* __restrict__ wt,
                                                float* __restrict__ out) {
    extern __shared__ char smem[];
    const int t = threadIdx.x;
    const int lane = t & 63;
    const int wid = t >> 6;
    const int wm = wid >> 1;          // 0..3 (co)
    const int wn = wid & 1;           // 0..1 (p)
    const bool lw = (t < 384);        // waves 0..5: 4 loads/stage, else 3
    const int bid = blockIdx.x;
    const int blk = (bid & 7) * (NBLK / 8) + (bid >> 3);   // XCD-chunked (bijective)
    const int n = blk / 14;
    const int pq = blk % 14;
    const int sp0 = pq * BNP;
    const int h0 = pq * 4;

    // staging: chunk c -> row=c>>2, slot=c&3, src chunk kc=(slot-(row>>1))&3.
    int a_off[2], x_off[2];
    #pragma unroll
    for (int i = 0; i < 2; ++i) {
        const int c = t + 512 * i;
        const int row = c >> 2;
        const int kc = ((c & 3) - (row >> 1)) & 3;
        a_off[i] = row * C_ + kc * 16;
    }
    {
        int c = t;
        int row = c >> 2;
        int kc = ((c & 3) - (row >> 1)) & 3;
        x_off[0] = ((n * HP + h0 + row / W_) * HP + (row % W_)) * C_ + kc * 16;
        c = t + 512;
        row = c >> 2;
        const int rowc = (row < BNP) ? row : 0;
        kc = ((c & 3) - (row >> 1)) & 3;
        x_off[1] = ((n * HP + h0 + rowc / W_) * HP + (rowc % W_)) * C_ + kc * 16;
    }

    // fragment-read byte offsets (64B rows, slot=(g+(r>>1))&3)
    const int g = lane >> 4;
    int aoff[4], boff[7];
    #pragma unroll
    for (int m = 0; m < 4; ++m) {
        const int r = wm * 64 + m * 16 + (lane & 15);
        aoff[m] = r * 64 + (((g + (r >> 1)) & 3) << 4);
    }
    #pragma unroll
    for (int nn = 0; nn < 7; ++nn) {
        const int r = wn * 112 + nn * 16 + (lane & 15);
        boff[nn] = r * 64 + (((g + (r >> 1)) & 3) << 4);
    }

    int32x4 acc[4][7];
    #pragma unroll
    for (int m = 0; m < 4; ++m)
        #pragma unroll
        for (int nn = 0; nn < 7; ++nn)
            acc[m][nn] = (int32x4){0, 0, 0, 0};

    auto sstage = [&](int u) {
        const int cbh = u / 9;
        const int tap = u - cbh * 9;
        const int kh = tap / 3, kw = tap - kh * 3;
        const int koff = cbh * 64;
        const int q = u & 1;
        char* Aq = smem + q * 16384;
        char* Bq = smem + 32768 + q * 14336;
        const unsigned char* asrc = wt + (size_t)tap * (C_ * C_) + koff;
        const unsigned char* bsrc = xt + (kh * HP + kw) * C_ + koff;
        GLOAD_LDS16(asrc + a_off[0], Aq + t * 16);
        GLOAD_LDS16(asrc + a_off[1], Aq + (t + 512) * 16);
        GLOAD_LDS16(bsrc + x_off[0], Bq + t * 16);
        if (lw)
            GLOAD_LDS16(bsrc + x_off[1], Bq + (t + 512) * 16);
    };

    auto compute = [&](int u) {
        const char* Aq = smem + (u & 1) * 16384;
        const char* Bq = smem + 32768 + (u & 1) * 14336;
        int32x4 af[4], bf[7];
        #pragma unroll
        for (int m = 0; m < 4; ++m)
            af[m] = *reinterpret_cast<const int32x4*>(Aq + aoff[m]);
        #pragma unroll
        for (int nn = 0; nn < 7; ++nn)
            bf[nn] = *reinterpret_cast<const int32x4*>(Bq + boff[nn]);
        __builtin_amdgcn_s_setprio(1);
        #pragma unroll
        for (int m = 0; m < 4; ++m)
            #pragma unroll
            for (int nn = 0; nn < 7; ++nn)
                acc[m][nn] = __builtin_amdgcn_mfma_i32_16x16x64_i8(
                    af[m], bf[nn], acc[m][nn], 0, 0, 0);
        __builtin_amdgcn_s_setprio(0);
    };

    // dbuf pipeline: stage(0); {sync; stage(u+1); compute(u)} x 36
    sstage(0);
    __syncthreads();                      // stage(0) landed (barrier drains vmcnt)
    for (int u = 0; u < NSUB; ++u) {
        if (u + 1 < NSUB) sstage(u + 1);  // writes buf^1 (not being read)
        compute(u);
        __syncthreads();                  // all reads of buf done + stage landed
    }

    // epilogue: D col = lane&15 (p), row = (lane>>4)*4 + j (co); scale by 1/26
    #pragma unroll
    for (int m = 0; m < 4; ++m) {
        #pragma unroll
        for (int j = 0; j < 4; ++j) {
            const int co = wm * 64 + m * 16 + (lane >> 4) * 4 + j;
            float* op = out + (size_t)(n * C_ + co) * SPATIAL + sp0 + wn * 112 + (lane & 15);
            #pragma unroll
            for (int nn = 0; nn < 7; ++nn)
                op[nn * 16] = (float)acc[m][nn][j] * QINV;
        }
    }
}

// ---------------- fallback (round-1 f32 direct conv) ----------------

__global__ __launch_bounds__(128) void bconv_f32_kernel(
    const float* __restrict__ x,
    const float* __restrict__ w,
    float* __restrict__ out)
{
    const int tx = threadIdx.x;
    const int ty = threadIdx.y;
    const int nc = blockIdx.x;
    const int co = nc & 255;
    const int h  = blockIdx.y * 8 + ty;
    const int w0 = tx * 4;
    if (tx >= 14) return;

    const float* xn = x + (size_t)(nc >> 8) * (C_ * H_ * W_);
    const float* wc = w + (size_t)co * (C_ * 9);
    float acc0 = 0.f, acc1 = 0.f, acc2 = 0.f, acc3 = 0.f;
    const bool rv0 = (h > 0), rv2 = (h < H_ - 1);
    const bool cvL = (tx != 0), cvR = (tx != 13);

    for (int ci = 0; ci < C_; ++ci) {
        const float* xc = xn + ci * (H_ * W_);
        const float* wk = wc + ci * 9;
        float v[3][6];
        #pragma unroll
        for (int r = 0; r < 3; ++r) {
            const bool rv = (r == 0) ? rv0 : (r == 2) ? rv2 : true;
            if (rv) {
                const float* rp = xc + (h + r - 1) * W_;
                const float4 m = *reinterpret_cast<const float4*>(rp + w0);
                v[r][1] = m.x; v[r][2] = m.y; v[r][3] = m.z; v[r][4] = m.w;
                v[r][0] = cvL ? rp[w0 - 1] : -1.0f;
                v[r][5] = cvR ? rp[w0 + 4] : -1.0f;
            } else {
                #pragma unroll
                for (int j = 0; j < 6; ++j) v[r][j] = -1.0f;
            }
        }
        #pragma unroll
        for (int r = 0; r < 3; ++r)
            #pragma unroll
            for (int c = 0; c < 3; ++c) {
                const float s = (wk[r * 3 + c] >= 0.f) ? 1.0f : -1.0f;
                acc0 = fmaf(s, v[r][c + 0], acc0);
                acc1 = fmaf(s, v[r][c + 1], acc1);
                acc2 = fmaf(s, v[r][c + 2], acc2);
                acc3 = fmaf(s, v[r][c + 3], acc3);
            }
    }
    float* op = out + ((size_t)nc * H_ + h) * W_ + w0;
    *reinterpret_cast<float4*>(op) = make_float4(acc0, acc1, acc2, acc3);
}

// ---------------- launch ----------------

extern "C" void kernel_launch(void* const* d_in, const int* in_sizes, int n_in,
                              void* d_out, int out_size, void* d_ws, size_t ws_size,
                              hipStream_t stream) {
    const float* x = (const float*)d_in[0];
    const float* w = (const float*)d_in[1];
    float* out = (float*)d_out;

    const size_t XT_OFF = 2u * 1024u * 1024u;                 // wt region (590KB)
    const size_t XT_BYTES = (size_t)N_ * HP * HP * C_;        // 27,557,888 (i8)
    const size_t NEEDED = XT_OFF + XT_BYTES;
    const int LDS_BYTES = 61440;   // A 2x16KB + B 2x14KB -> 2 blocks/CU

    if (ws_size >= NEEDED) {
        char* wt = (char*)d_ws;
        unsigned char* xt = (unsigned char*)((char*)d_ws + XT_OFF);
        hipFuncSetAttribute((const void*)&bgemm,
                            hipFuncAttributeMaxDynamicSharedMemorySize, LDS_BYTES);
        xform_w<<<256, 256, 0, stream>>>(w, wt);
        xform_x<<<N_ * H_, 256, 0, stream>>>(x, xt);
        bgemm<<<NBLK, 512, LDS_BYTES, stream>>>(xt, (const unsigned char*)wt, out);
    } else {
        dim3 block(16, 8);
        dim3 grid(N_ * 256, H_ / 8);
        bconv_f32_kernel<<<grid, block, 0, stream>>>(x, w, out);
    }
}

// Round 11
// 143.504 us; speedup vs baseline: 3.0952x; 3.0952x over previous
//
#include <hip/hip_runtime.h>

// Binary-weight 3x3 conv via implicit GEMM on int8 MFMA.
// out[co, p] = (1/26) * sum_k wb[co,k] * q26(im2col(x))[k,p],  exact i32 accum.
// Round 11: SINGLE-WAVE blocks, zero barriers. 3584 blocks of 64 threads;
// each wave owns a 64co x 112p tile (4x7 16x16x64 frags, acc 112 VGPR).
// A: global->VGPR double-banked (wt is 576KB, L2-resident). B: private
// per-wave LDS dbuf 2x7KB via global_load_lds (verified swizzle). Only
// per-wave WAITV(0) gates; 8 independent wave-blocks/CU hide all latency
// (m97/m114 implicit overlap). setprio kept (independent-wave regime).

#define N_ 32
#define C_ 256
#define H_ 56
#define W_ 56
#define HP 58
#define SPATIAL (H_ * W_)          // 3136
#define P_TOTAL (N_ * SPATIAL)     // 100352
#define WP 112                     // p per wave-block
#define NBLKW (P_TOTAL / WP * 4)   // 896 p-tiles x 4 co-groups = 3584
#define QSCALE 26.0f
#define QINV (1.0f / 26.0f)

typedef __attribute__((ext_vector_type(4))) int int32x4;

#define GLOAD_LDS16(g, l) __builtin_amdgcn_global_load_lds(                 \
    (const __attribute__((address_space(1))) void*)(g),                     \
    (__attribute__((address_space(3))) void*)(l), 16, 0, 0)

#define WAITV0() asm volatile("s_waitcnt vmcnt(0)" ::: "memory")

// ---------------- prep kernels (unchanged, verified R7) ----------------

__global__ void xform_w(const float* __restrict__ w, char* __restrict__ wt) {
    const int co = blockIdx.x;
    const int ci = threadIdx.x;
    const float* wp = w + ((size_t)co * C_ + ci) * 9;
    #pragma unroll
    for (int tap = 0; tap < 9; ++tap)
        wt[((size_t)tap * C_ + co) * C_ + ci] = (wp[tap] >= 0.f) ? (char)1 : (char)-1;
}

// NCHW f32 -> padded NHWC i8 (q = clamp(rint(26x)); pad = -26). Block = (n,h).
__global__ __launch_bounds__(256) void xform_x(const float* __restrict__ x,
                                               unsigned char* __restrict__ xt) {
    __shared__ unsigned char lds8[64 * 272];   // [w][ci], stride 272
    const int b = blockIdx.x;                  // n*56 + h
    const int n = b / H_;
    const int h = b - n * H_;
    const int t = threadIdx.x;
    const int wq = t >> 6;                     // ci quarter
    const int wv = t & 63;                     // w lane
    const float* xp = x + (((size_t)n * C_ + wq * 64) * H_ + h) * W_ + wv;

    #pragma unroll 4
    for (int c4 = 0; c4 < 64; c4 += 4) {
        unsigned int pk = 0;
        #pragma unroll
        for (int j = 0; j < 4; ++j) {
            float v = (wv < W_) ? xp[(size_t)(c4 + j) * SPATIAL] : 0.f;
            int q = (int)rintf(v * QSCALE);
            q = q < -127 ? -127 : (q > 127 ? 127 : q);
            pk |= ((unsigned int)(q & 255)) << (8 * j);
        }
        if (wv < W_)
            *reinterpret_cast<unsigned int*>(&lds8[wv * 272 + wq * 64 + c4]) = pk;
    }
    __syncthreads();

    unsigned char* rowp = xt + (((size_t)n * HP + h + 1) * HP) * C_;
    {
        const int ww = t & 63, cq = t >> 6;
        if (ww < W_) {
            #pragma unroll
            for (int j = 0; j < 4; ++j) {
                int32x4 v = *reinterpret_cast<const int32x4*>(
                    &lds8[ww * 272 + cq * 64 + j * 16]);
                *reinterpret_cast<int32x4*>(rowp + (size_t)(ww + 1) * C_ + cq * 64 + j * 16) = v;
            }
        }
    }
    if (t < 64) {   // pad cols w=0 and w=57 (0xE6 = -26)
        reinterpret_cast<unsigned int*>(rowp)[t] = 0xE6E6E6E6u;
        reinterpret_cast<unsigned int*>(rowp + (size_t)57 * C_)[t] = 0xE6E6E6E6u;
    }
    if (h == 0) {
        unsigned int* r0  = reinterpret_cast<unsigned int*>(xt + ((size_t)n * HP) * HP * C_);
        unsigned int* r57 = reinterpret_cast<unsigned int*>(xt + (((size_t)n * HP + 57) * HP) * C_);
        for (int idx = t; idx < HP * C_ / 4; idx += 256) {
            r0[idx]  = 0xE6E6E6E6u;
            r57[idx] = 0xE6E6E6E6u;
        }
    }
}

// ---------------- main GEMM: 1 wave per block, no barriers ----------------
// blk (after XCD swizzle): cog = blk&3 (co group, fast -> 4 consecutive
// blocks share the p-tile's xt bytes in L2), ptile = blk>>2 (0..895).
// Step u (36): cbh = u/9 (64-ci slice), tap = u%9 (fastest: L2 tap reuse).

__global__ __launch_bounds__(64, 2) void bgemm(const unsigned char* __restrict__ xt,
                                               const unsigned char* __restrict__ wt,
                                               float* __restrict__ out) {
    extern __shared__ char smem[];             // 2 x 7168 B (B dbuf)
    const int lane = threadIdx.x;
    const int bid = blockIdx.x;
    const int blk = (bid & 7) * (NBLKW / 8) + (bid >> 3);   // XCD-chunked, bijective
    const int cog = blk & 3;
    const int ptile = blk >> 2;                // 0..895
    const int n = ptile / 28;
    const int pr = ptile - n * 28;             // row-pair index
    const int h0 = pr * 2;
    const int sp0 = pr * WP;
    const int co0 = cog * 64;

    // ---- B staging offsets: chunk c = i*64+lane; row=c>>2, slot=c&3,
    //      src chunk kc=(slot-(row>>1))&3 (verified swizzle) ----
    int x_off[7];
    #pragma unroll
    for (int i = 0; i < 7; ++i) {
        const int c = i * 64 + lane;
        const int row = c >> 2;                // 0..111
        const int kc = ((c & 3) - (row >> 1)) & 3;
        const int hh = (row >= 56) ? 1 : 0;
        const int ww = row - hh * 56;
        x_off[i] = ((n * HP + h0 + hh) * HP + ww) * C_ + kc * 16;
    }

    const int g = lane >> 4;
    // ---- A per-lane global pointers (row co, k-quarter g) ----
    const unsigned char* aptr[4];
    #pragma unroll
    for (int m = 0; m < 4; ++m)
        aptr[m] = wt + (size_t)(co0 + m * 16 + (lane & 15)) * C_ + g * 16;

    // ---- B fragment-read byte offsets (64B rows, slot=(g+(r>>1))&3) ----
    int boff[7];
    #pragma unroll
    for (int nn = 0; nn < 7; ++nn) {
        const int r = nn * 16 + (lane & 15);
        boff[nn] = r * 64 + (((g + (r >> 1)) & 3) << 4);
    }

    int32x4 acc[4][7];
    #pragma unroll
    for (int m = 0; m < 4; ++m)
        #pragma unroll
        for (int nn = 0; nn < 7; ++nn)
            acc[m][nn] = (int32x4){0, 0, 0, 0};

    auto bstage = [&](int u, int qb) {
        const int cbh = u / 9;
        const int tap = u - cbh * 9;
        const int kh = tap / 3, kw = tap - kh * 3;
        char* Bq = smem + qb * 7168;
        const unsigned char* bsrc = xt + (kh * HP + kw) * C_ + cbh * 64;
        #pragma unroll
        for (int i = 0; i < 7; ++i)
            GLOAD_LDS16(bsrc + x_off[i], Bq + i * 1024 + lane * 16);
    };

    int32x4 aA[4], aB[4];

#define ALOAD(AB, u_) {                                                     \
        const int uu_ = (u_);                                               \
        const int cbh_ = uu_ / 9;                                           \
        const size_t o_ = (size_t)(uu_ - cbh_ * 9) * (C_ * C_) + cbh_ * 64; \
        _Pragma("unroll")                                                   \
        for (int m_ = 0; m_ < 4; ++m_)                                      \
            AB[m_] = *reinterpret_cast<const int32x4*>(aptr[m_] + o_);      \
    }

#define READB(BF, qb) {                                                     \
        const char* Bq_ = smem + (qb) * 7168;                               \
        _Pragma("unroll")                                                   \
        for (int n_ = 0; n_ < 7; ++n_)                                      \
            BF[n_] = *reinterpret_cast<const int32x4*>(Bq_ + boff[n_]);     \
    }

#define MFMA28(AF, BF) {                                                    \
        __builtin_amdgcn_s_setprio(1);                                      \
        _Pragma("unroll")                                                   \
        for (int m_ = 0; m_ < 4; ++m_)                                      \
            _Pragma("unroll")                                               \
            for (int n_ = 0; n_ < 7; ++n_)                                  \
                acc[m_][n_] = __builtin_amdgcn_mfma_i32_16x16x64_i8(        \
                    AF[m_], BF[n_], acc[m_][n_], 0, 0, 0);                  \
        __builtin_amdgcn_s_setprio(0);                                      \
    }

    // prologue: A(0) -> aA, B(0) -> buf0
    ALOAD(aA, 0);
    bstage(0, 0);

    int32x4 bf[7];
    for (int it = 0; it < 18; ++it) {
        const int u = 2 * it;
        // even step u: consume buf0 + aA; prefetch A(u+1), B(u+1)->buf1
        WAITV0();                      // B(u) landed (+ A(u) regs retired)
        READB(bf, 0);
        ALOAD(aB, u + 1);
        bstage(u + 1, 1);
        MFMA28(aA, bf);
        // odd step u+1: consume buf1 + aB; prefetch A(u+2), B(u+2)->buf0
        WAITV0();
        READB(bf, 1);
        if (it < 17) {
            ALOAD(aA, u + 2);
            bstage(u + 2, 0);          // buf0 reads (even step) long retired
        }
        MFMA28(aB, bf);
    }

#undef ALOAD
#undef READB
#undef MFMA28

    // epilogue: D col = lane&15 (p), row = (lane>>4)*4 + j (co); scale 1/26
    #pragma unroll
    for (int m = 0; m < 4; ++m) {
        #pragma unroll
        for (int j = 0; j < 4; ++j) {
            const int co = co0 + m * 16 + (lane >> 4) * 4 + j;
            float* op = out + (size_t)(n * C_ + co) * SPATIAL + sp0 + (lane & 15);
            #pragma unroll
            for (int nn = 0; nn < 7; ++nn)
                op[nn * 16] = (float)acc[m][nn][j] * QINV;
        }
    }
}

// ---------------- fallback (round-1 f32 direct conv) ----------------

__global__ __launch_bounds__(128) void bconv_f32_kernel(
    const float* __restrict__ x,
    const float* __restrict__ w,
    float* __restrict__ out)
{
    const int tx = threadIdx.x;
    const int ty = threadIdx.y;
    const int nc = blockIdx.x;
    const int co = nc & 255;
    const int h  = blockIdx.y * 8 + ty;
    const int w0 = tx * 4;
    if (tx >= 14) return;

    const float* xn = x + (size_t)(nc >> 8) * (C_ * H_ * W_);
    const float* wc = w + (size_t)co * (C_ * 9);
    float acc0 = 0.f, acc1 = 0.f, acc2 = 0.f, acc3 = 0.f;
    const bool rv0 = (h > 0), rv2 = (h < H_ - 1);
    const bool cvL = (tx != 0), cvR = (tx != 13);

    for (int ci = 0; ci < C_; ++ci) {
        const float* xc = xn + ci * (H_ * W_);
        const float* wk = wc + ci * 9;
        float v[3][6];
        #pragma unroll
        for (int r = 0; r < 3; ++r) {
            const bool rv = (r == 0) ? rv0 : (r == 2) ? rv2 : true;
            if (rv) {
                const float* rp = xc + (h + r - 1) * W_;
                const float4 m = *reinterpret_cast<const float4*>(rp + w0);
                v[r][1] = m.x; v[r][2] = m.y; v[r][3] = m.z; v[r][4] = m.w;
                v[r][0] = cvL ? rp[w0 - 1] : -1.0f;
                v[r][5] = cvR ? rp[w0 + 4] : -1.0f;
            } else {
                #pragma unroll
                for (int j = 0; j < 6; ++j) v[r][j] = -1.0f;
            }
        }
        #pragma unroll
        for (int r = 0; r < 3; ++r)
            #pragma unroll
            for (int c = 0; c < 3; ++c) {
                const float s = (wk[r * 3 + c] >= 0.f) ? 1.0f : -1.0f;
                acc0 = fmaf(s, v[r][c + 0], acc0);
                acc1 = fmaf(s, v[r][c + 1], acc1);
                acc2 = fmaf(s, v[r][c + 2], acc2);
                acc3 = fmaf(s, v[r][c + 3], acc3);
            }
    }
    float* op = out + ((size_t)nc * H_ + h) * W_ + w0;
    *reinterpret_cast<float4*>(op) = make_float4(acc0, acc1, acc2, acc3);
}

// ---------------- launch ----------------

extern "C" void kernel_launch(void* const* d_in, const int* in_sizes, int n_in,
                              void* d_out, int out_size, void* d_ws, size_t ws_size,
                              hipStream_t stream) {
    const float* x = (const float*)d_in[0];
    const float* w = (const float*)d_in[1];
    float* out = (float*)d_out;

    const size_t XT_OFF = 2u * 1024u * 1024u;                 // wt region (590KB)
    const size_t XT_BYTES = (size_t)N_ * HP * HP * C_;        // 27,557,888 (i8)
    const size_t NEEDED = XT_OFF + XT_BYTES;
    const int LDS_BYTES = 2 * 7168;   // per-wave B dbuf (14,336 B)

    if (ws_size >= NEEDED) {
        char* wt = (char*)d_ws;
        unsigned char* xt = (unsigned char*)((char*)d_ws + XT_OFF);
        hipFuncSetAttribute((const void*)&bgemm,
                            hipFuncAttributeMaxDynamicSharedMemorySize, LDS_BYTES);
        xform_w<<<256, 256, 0, stream>>>(w, wt);
        xform_x<<<N_ * H_, 256, 0, stream>>>(x, xt);
        bgemm<<<NBLKW, 64, LDS_BYTES, stream>>>(xt, (const unsigned char*)wt, out);
    } else {
        dim3 block(16, 8);
        dim3 grid(N_ * 256, H_ / 8);
        bconv_f32_kernel<<<grid, block, 0, stream>>>(x, w, out);
    }
}

// Round 13
// 105.068 us; speedup vs baseline: 4.2274x; 1.3658x over previous
//
#include <hip/hip_runtime.h>

// Binary-weight 3x3 conv via implicit GEMM on int8 MFMA.
// out[co, p] = (1/26) * sum_k wb[co,k] * q26(im2col(x))[k,p],  exact i32 accum.
// Round 13: exact restore of the round-7 kernel (fastest fully-passing config:
// 105.2us total, bgemm 74.8us, absmax 3.125). Round 12's added diagnostic
// dispatches caused post-timing divergence (replay nondeterminism); reverting
// to the proven single-variant build.
// Structure: 36 sub-steps of BK=64(ci), quad LDS buffers (A 4x16KB + B 4x14KB),
// reg-double-banked MFMA, counted vmcnt (never 0 mid-loop), one barrier/step.

#define N_ 32
#define C_ 256
#define H_ 56
#define W_ 56
#define HP 58
#define SPATIAL (H_ * W_)          // 3136
#define P_TOTAL (N_ * SPATIAL)     // 100352
#define BNP 224
#define NBLK (P_TOTAL / BNP)       // 448
#define NSUB 36                    // 4 ci-slices(64) * 9 taps
#define QSCALE 26.0f
#define QINV (1.0f / 26.0f)

typedef __attribute__((ext_vector_type(4))) int int32x4;

#define GLOAD_LDS16(g, l) __builtin_amdgcn_global_load_lds(                 \
    (const __attribute__((address_space(1))) void*)(g),                     \
    (__attribute__((address_space(3))) void*)(l), 16, 0, 0)

#define WAITV(N) asm volatile("s_waitcnt vmcnt(" #N ")" ::: "memory")

// ---------------- prep kernels ----------------

__global__ void xform_w(const float* __restrict__ w, char* __restrict__ wt) {
    const int co = blockIdx.x;
    const int ci = threadIdx.x;
    const float* wp = w + ((size_t)co * C_ + ci) * 9;
    #pragma unroll
    for (int tap = 0; tap < 9; ++tap)
        wt[((size_t)tap * C_ + co) * C_ + ci] = (wp[tap] >= 0.f) ? (char)1 : (char)-1;
}

// NCHW f32 -> padded NHWC i8 (q = clamp(rint(26x)); pad = -26). Block = (n,h).
__global__ __launch_bounds__(256) void xform_x(const float* __restrict__ x,
                                               unsigned char* __restrict__ xt) {
    __shared__ unsigned char lds8[64 * 272];   // [w][ci], stride 272 (16-mult)
    const int b = blockIdx.x;                  // n*56 + h
    const int n = b / H_;
    const int h = b - n * H_;
    const int t = threadIdx.x;
    const int wq = t >> 6;                     // ci quarter
    const int wv = t & 63;                     // w lane
    const float* xp = x + (((size_t)n * C_ + wq * 64) * H_ + h) * W_ + wv;

    #pragma unroll 4
    for (int c4 = 0; c4 < 64; c4 += 4) {
        unsigned int pk = 0;
        #pragma unroll
        for (int j = 0; j < 4; ++j) {
            float v = (wv < W_) ? xp[(size_t)(c4 + j) * SPATIAL] : 0.f;
            int q = (int)rintf(v * QSCALE);
            q = q < -127 ? -127 : (q > 127 ? 127 : q);
            pk |= ((unsigned int)(q & 255)) << (8 * j);
        }
        if (wv < W_)
            *reinterpret_cast<unsigned int*>(&lds8[wv * 272 + wq * 64 + c4]) = pk;
    }
    __syncthreads();

    unsigned char* rowp = xt + (((size_t)n * HP + h + 1) * HP) * C_;
    {   // interior: w = 1..56, 64B (4x16B) per thread along ci
        const int ww = t & 63, cq = t >> 6;
        if (ww < W_) {
            #pragma unroll
            for (int j = 0; j < 4; ++j) {
                int32x4 v = *reinterpret_cast<const int32x4*>(
                    &lds8[ww * 272 + cq * 64 + j * 16]);
                *reinterpret_cast<int32x4*>(rowp + (size_t)(ww + 1) * C_ + cq * 64 + j * 16) = v;
            }
        }
    }
    if (t < 64) {   // pad cols w=0 and w=57 (0xE6 = -26)
        reinterpret_cast<unsigned int*>(rowp)[t] = 0xE6E6E6E6u;
        reinterpret_cast<unsigned int*>(rowp + (size_t)57 * C_)[t] = 0xE6E6E6E6u;
    }
    if (h == 0) {   // pad rows 0 and 57 once per n
        unsigned int* r0  = reinterpret_cast<unsigned int*>(xt + ((size_t)n * HP) * HP * C_);
        unsigned int* r57 = reinterpret_cast<unsigned int*>(xt + (((size_t)n * HP + 57) * HP) * C_);
        for (int idx = t; idx < HP * C_ / 4; idx += 256) {
            r0[idx]  = 0xE6E6E6E6u;
            r57[idx] = 0xE6E6E6E6u;
        }
    }
}

// ---------------- main GEMM ----------------
// grid = 448 blocks (XCD-swizzled), 512 threads = 8 waves (4 co x 2 p).
// Wave (wm,wn): 64 co x 112 p = 4x7 16x16x64 i8 fragments.
// Sub-step u: cbh = u/9 (64-ci slice), tap = u%9; quad LDS buffers q = u&3.

__global__ __launch_bounds__(512, 2) void bgemm(const unsigned char* __restrict__ xt,
                                                const unsigned char* __restrict__ wt,
                                                float* __restrict__ out) {
    extern __shared__ char smem[];
    const int t = threadIdx.x;
    const int lane = t & 63;
    const int wid = t >> 6;
    const int wm = wid >> 1;          // 0..3 (co)
    const int wn = wid & 1;           // 0..1 (p)
    const bool lw = (t < 384);        // waves 0..5: 4 loads/stage, else 3
    const int bid = blockIdx.x;
    const int blk = (bid & 7) * (NBLK / 8) + (bid >> 3);   // XCD-chunked (bijective)
    const int n = blk / 14;
    const int pq = blk % 14;
    const int sp0 = pq * BNP;
    const int h0 = pq * 4;

    // staging: chunk c -> row=c>>2, slot=c&3, src chunk kc=(slot-(row>>1))&3.
    // offsets in BYTES (row stride = C_ = 256 B, 64B staged per row).
    int a_off[2], x_off[2];
    #pragma unroll
    for (int i = 0; i < 2; ++i) {
        const int c = t + 512 * i;
        const int row = c >> 2;
        const int kc = ((c & 3) - (row >> 1)) & 3;
        a_off[i] = row * C_ + kc * 16;
    }
    {
        int c = t;
        int row = c >> 2;
        int kc = ((c & 3) - (row >> 1)) & 3;
        x_off[0] = ((n * HP + h0 + row / W_) * HP + (row % W_)) * C_ + kc * 16;
        c = t + 512;
        row = c >> 2;
        const int rowc = (row < BNP) ? row : 0;
        kc = ((c & 3) - (row >> 1)) & 3;
        x_off[1] = ((n * HP + h0 + rowc / W_) * HP + (rowc % W_)) * C_ + kc * 16;
    }

    // fragment-read byte offsets (64B rows, slot=(g+(r>>1))&3)
    const int g = lane >> 4;
    int aoff[4], boff[7];
    #pragma unroll
    for (int m = 0; m < 4; ++m) {
        const int r = wm * 64 + m * 16 + (lane & 15);
        aoff[m] = r * 64 + (((g + (r >> 1)) & 3) << 4);
    }
    #pragma unroll
    for (int nn = 0; nn < 7; ++nn) {
        const int r = wn * 112 + nn * 16 + (lane & 15);
        boff[nn] = r * 64 + (((g + (r >> 1)) & 3) << 4);
    }

    int32x4 acc[4][7];
    #pragma unroll
    for (int m = 0; m < 4; ++m)
        #pragma unroll
        for (int nn = 0; nn < 7; ++nn)
            acc[m][nn] = (int32x4){0, 0, 0, 0};

    auto sstage = [&](int u) {
        const int cbh = u / 9;
        const int tap = u - cbh * 9;
        const int kh = tap / 3, kw = tap - kh * 3;
        const int koff = cbh * 64;
        const int q = u & 3;
        char* Aq = smem + q * 16384;
        char* Bq = smem + 65536 + q * 14336;
        const unsigned char* asrc = wt + (size_t)tap * (C_ * C_) + koff;
        const unsigned char* bsrc = xt + (kh * HP + kw) * C_ + koff;
        GLOAD_LDS16(asrc + a_off[0], Aq + t * 16);
        GLOAD_LDS16(asrc + a_off[1], Aq + (t + 512) * 16);
        GLOAD_LDS16(bsrc + x_off[0], Bq + t * 16);
        if (lw)
            GLOAD_LDS16(bsrc + x_off[1], Bq + (t + 512) * 16);
    };

    int32x4 a0[4], b0[7], a1[4], b1[7];

#define READFRAGS(AF, BF, q) {                                              \
        const char* Aq_ = smem + (q) * 16384;                               \
        const char* Bq_ = smem + 65536 + (q) * 14336;                       \
        _Pragma("unroll")                                                   \
        for (int m_ = 0; m_ < 4; ++m_)                                      \
            AF[m_] = *reinterpret_cast<const int32x4*>(Aq_ + aoff[m_]);     \
        _Pragma("unroll")                                                   \
        for (int n_ = 0; n_ < 7; ++n_)                                      \
            BF[n_] = *reinterpret_cast<const int32x4*>(Bq_ + boff[n_]);     \
    }

#define MFMA28(AF, BF) {                                                    \
        __builtin_amdgcn_sched_barrier(0);                                  \
        __builtin_amdgcn_s_setprio(1);                                      \
        _Pragma("unroll")                                                   \
        for (int m_ = 0; m_ < 4; ++m_)                                      \
            _Pragma("unroll")                                               \
            for (int n_ = 0; n_ < 7; ++n_)                                  \
                acc[m_][n_] = __builtin_amdgcn_mfma_i32_16x16x64_i8(        \
                    AF[m_], BF[n_], acc[m_][n_], 0, 0, 0);                  \
        __builtin_amdgcn_s_setprio(0);                                      \
        __builtin_amdgcn_sched_barrier(0);                                  \
    }

    // prologue: 3 stages in flight; land stage(0); read frags(0) -> bank0
    sstage(0); sstage(1); sstage(2);
    if (lw) WAITV(8); else WAITV(6);
    __builtin_amdgcn_s_barrier();
    READFRAGS(a0, b0, 0);

    for (int it = 0; it < 17; ++it) {
        const int u = 2 * it;
        // even step u: MFMA bank0 (frags u), read frags(u+1)->bank1, stage(u+3)
        if (lw) WAITV(4); else WAITV(3);
        __builtin_amdgcn_s_barrier();
        READFRAGS(a1, b1, (u + 1) & 3);
        sstage(u + 3);
        MFMA28(a0, b0);
        // odd step u+1: MFMA bank1, read frags(u+2)->bank0, stage(u+4)
        if (lw) WAITV(4); else WAITV(3);
        __builtin_amdgcn_s_barrier();
        READFRAGS(a0, b0, (u + 2) & 3);
        if (it < 16) sstage(u + 4);
        MFMA28(a1, b1);
    }
    // u = 34, 35
    WAITV(0);
    __builtin_amdgcn_s_barrier();
    READFRAGS(a1, b1, 3);
    MFMA28(a0, b0);
    MFMA28(a1, b1);

#undef READFRAGS
#undef MFMA28

    // epilogue: D col = lane&15 (p), row = (lane>>4)*4 + j (co); scale by 1/26
    #pragma unroll
    for (int m = 0; m < 4; ++m) {
        #pragma unroll
        for (int j = 0; j < 4; ++j) {
            const int co = wm * 64 + m * 16 + (lane >> 4) * 4 + j;
            float* op = out + (size_t)(n * C_ + co) * SPATIAL + sp0 + wn * 112 + (lane & 15);
            #pragma unroll
            for (int nn = 0; nn < 7; ++nn)
                op[nn * 16] = (float)acc[m][nn][j] * QINV;
        }
    }
}

// ---------------- fallback (round-1 f32 direct conv) ----------------

__global__ __launch_bounds__(128) void bconv_f32_kernel(
    const float* __restrict__ x,
    const float* __restrict__ w,
    float* __restrict__ out)
{
    const int tx = threadIdx.x;
    const int ty = threadIdx.y;
    const int nc = blockIdx.x;
    const int co = nc & 255;
    const int h  = blockIdx.y * 8 + ty;
    const int w0 = tx * 4;
    if (tx >= 14) return;

    const float* xn = x + (size_t)(nc >> 8) * (C_ * H_ * W_);
    const float* wc = w + (size_t)co * (C_ * 9);
    float acc0 = 0.f, acc1 = 0.f, acc2 = 0.f, acc3 = 0.f;
    const bool rv0 = (h > 0), rv2 = (h < H_ - 1);
    const bool cvL = (tx != 0), cvR = (tx != 13);

    for (int ci = 0; ci < C_; ++ci) {
        const float* xc = xn + ci * (H_ * W_);
        const float* wk = wc + ci * 9;
        float v[3][6];
        #pragma unroll
        for (int r = 0; r < 3; ++r) {
            const bool rv = (r == 0) ? rv0 : (r == 2) ? rv2 : true;
            if (rv) {
                const float* rp = xc + (h + r - 1) * W_;
                const float4 m = *reinterpret_cast<const float4*>(rp + w0);
                v[r][1] = m.x; v[r][2] = m.y; v[r][3] = m.z; v[r][4] = m.w;
                v[r][0] = cvL ? rp[w0 - 1] : -1.0f;
                v[r][5] = cvR ? rp[w0 + 4] : -1.0f;
            } else {
                #pragma unroll
                for (int j = 0; j < 6; ++j) v[r][j] = -1.0f;
            }
        }
        #pragma unroll
        for (int r = 0; r < 3; ++r)
            #pragma unroll
            for (int c = 0; c < 3; ++c) {
                const float s = (wk[r * 3 + c] >= 0.f) ? 1.0f : -1.0f;
                acc0 = fmaf(s, v[r][c + 0], acc0);
                acc1 = fmaf(s, v[r][c + 1], acc1);
                acc2 = fmaf(s, v[r][c + 2], acc2);
                acc3 = fmaf(s, v[r][c + 3], acc3);
            }
    }
    float* op = out + ((size_t)nc * H_ + h) * W_ + w0;
    *reinterpret_cast<float4*>(op) = make_float4(acc0, acc1, acc2, acc3);
}

// ---------------- launch ----------------

extern "C" void kernel_launch(void* const* d_in, const int* in_sizes, int n_in,
                              void* d_out, int out_size, void* d_ws, size_t ws_size,
                              hipStream_t stream) {
    const float* x = (const float*)d_in[0];
    const float* w = (const float*)d_in[1];
    float* out = (float*)d_out;

    const size_t XT_OFF = 2u * 1024u * 1024u;                 // wt region (590KB)
    const size_t XT_BYTES = (size_t)N_ * HP * HP * C_;        // 27,557,888 (i8)
    const size_t NEEDED = XT_OFF + XT_BYTES;
    const int LDS_BYTES = 122880;   // A 4x16KB + B 4x14KB

    if (ws_size >= NEEDED) {
        char* wt = (char*)d_ws;
        unsigned char* xt = (unsigned char*)((char*)d_ws + XT_OFF);
        hipFuncSetAttribute((const void*)&bgemm,
                            hipFuncAttributeMaxDynamicSharedMemorySize, LDS_BYTES);
        xform_w<<<256, 256, 0, stream>>>(w, wt);
        xform_x<<<N_ * H_, 256, 0, stream>>>(x, xt);
        bgemm<<<NBLK, 512, LDS_BYTES, stream>>>(xt, (const unsigned char*)wt, out);
    } else {
        dim3 block(16, 8);
        dim3 grid(N_ * 256, H_ / 8);
        bconv_f32_kernel<<<grid, block, 0, stream>>>(x, w, out);
    }
}